// Round 6
// baseline (132.580 us; speedup 1.0000x reference)
//
#include <hip/hip_runtime.h>

#define NATOM 96
#define EDIM  16
#define HDIM  64
#define BN    (32 * 96)   // B*N = 3072 atoms

// ---------------------------------------------------------------------------
// Kernel 1: per-atom precompute  u_a = x_a@W1[0:65]+b1,  v_a = x_a@W1[65:130]
// x_a = [h_a (64), q_a (1)]
// ---------------------------------------------------------------------------
__global__ void uv_kernel(const float* __restrict__ h,
                          const float* __restrict__ q,
                          const float* __restrict__ W1,
                          const float* __restrict__ b1,
                          float* __restrict__ u,
                          float* __restrict__ v) {
    int id = blockIdx.x * 256 + threadIdx.x;
    if (id >= BN * 32) return;
    int a = id >> 5;
    int m = id & 31;
    const float* ha = h + (size_t)a * HDIM;
    float qa = q[a];
    float su = b1[m];
    float sv = 0.f;
#pragma unroll 8
    for (int f = 0; f < HDIM; ++f) {
        float hf = ha[f];
        su = fmaf(hf, W1[f * 32 + m], su);
        sv = fmaf(hf, W1[(65 + f) * 32 + m], sv);
    }
    su = fmaf(qa, W1[64 * 32 + m], su);
    sv = fmaf(qa, W1[129 * 32 + m], sv);
    u[id] = su;
    v[id] = sv;
}

// ---------------------------------------------------------------------------
// Kernel 2: block = 384 threads = 4 rows (b,i) x 96 edges j; thread owns one
// edge. Both MLP directions accumulate in ONE merged k-loop so every scalar
// W2 value (SGPR, K$-cached) feeds 2 FMAs: 128B of weight stream per 128
// cycles of FMA. t = e@W1c shared between directions; b3 cancels.
// ---------------------------------------------------------------------------
__global__ __launch_bounds__(384) void edge_kernel(
    const float* __restrict__ e,
    const float* __restrict__ mask,
    const float* __restrict__ qin,
    const float* __restrict__ W1,
    const float* __restrict__ W2,
    const float* __restrict__ b2,
    const float* __restrict__ W3,
    const float* __restrict__ u,
    const float* __restrict__ v,
    float* __restrict__ qout)
{
    __shared__ float sVal[4][NATOM];

    const int tid = threadIdx.x;
    const int r   = tid / NATOM;          // 0..3: row within block
    const int j   = tid - r * NATOM;      // 0..95: edge target atom
    const int bi0 = blockIdx.x * 4;       // first (b,i) row of this block
    const int bi  = bi0 + r;
    const int b   = bi / NATOM;           // molecule (4-row group never crosses b)

    const float* __restrict__ W1c = W1 + 130 * 32;   // e-part of W1, 16x32

    // ---- mask load issued early (hide VMEM latency under the MLP) ----
    float mval = mask[(size_t)bi * NATOM + j];

    // ---- load e_ij (16 floats, coalesced: thread j consecutive) ----
    const float4* e4 = (const float4*)(e + ((size_t)bi * NATOM + j) * EDIM);
    float4 e0 = e4[0], e1 = e4[1], e2 = e4[2], e3 = e4[3];
    float ef[16];
    ef[0]  = e0.x; ef[1]  = e0.y; ef[2]  = e0.z; ef[3]  = e0.w;
    ef[4]  = e1.x; ef[5]  = e1.y; ef[6]  = e1.z; ef[7]  = e1.w;
    ef[8]  = e2.x; ef[9]  = e2.y; ef[10] = e2.z; ef[11] = e2.w;
    ef[12] = e3.x; ef[13] = e3.y; ef[14] = e3.z; ef[15] = e3.w;

    // ---- t = e @ W1c  (W1c via scalar loads) ----
    float t[32];
#pragma unroll
    for (int m = 0; m < 32; ++m) t[m] = 0.f;
#pragma unroll
    for (int f = 0; f < EDIM; ++f) {
        float ev = ef[f];
#pragma unroll
        for (int m = 0; m < 32; ++m)
            t[m] = fmaf(ev, W1c[f * 32 + m], t[m]);
    }

    const float4* ui4 = (const float4*)(u + (size_t)bi * 32);
    const float4* vi4 = (const float4*)(v + (size_t)bi * 32);
    const float4* uj4 = (const float4*)(u + ((size_t)(b * NATOM + j)) * 32);
    const float4* vj4 = (const float4*)(v + ((size_t)(b * NATOM + j)) * 32);

    // ---- z1 for both directions (t consumed here, registers freed) ----
    float z1ij[32], z1ji[32];
#pragma unroll
    for (int m4 = 0; m4 < 8; ++m4) {
        float4 a = ui4[m4];
        float4 c = vj4[m4];
        float4 d = uj4[m4];
        float4 g = vi4[m4];
        z1ij[4 * m4 + 0] = fmaxf(a.x + c.x + t[4 * m4 + 0], 0.f);
        z1ij[4 * m4 + 1] = fmaxf(a.y + c.y + t[4 * m4 + 1], 0.f);
        z1ij[4 * m4 + 2] = fmaxf(a.z + c.z + t[4 * m4 + 2], 0.f);
        z1ij[4 * m4 + 3] = fmaxf(a.w + c.w + t[4 * m4 + 3], 0.f);
        z1ji[4 * m4 + 0] = fmaxf(d.x + g.x + t[4 * m4 + 0], 0.f);
        z1ji[4 * m4 + 1] = fmaxf(d.y + g.y + t[4 * m4 + 1], 0.f);
        z1ji[4 * m4 + 2] = fmaxf(d.z + g.z + t[4 * m4 + 2], 0.f);
        z1ji[4 * m4 + 3] = fmaxf(d.w + g.w + t[4 * m4 + 3], 0.f);
    }

    // ---- layer 2, MERGED k-loop: each scalar W2 value feeds both dirs ----
    float aij[32], aji[32];
#pragma unroll
    for (int m = 0; m < 32; ++m) {
        float bb = b2[m];
        aij[m] = bb;
        aji[m] = bb;
    }
#pragma unroll
    for (int k = 0; k < 32; ++k) {
        float zij = z1ij[k];
        float zji = z1ji[k];
#pragma unroll
        for (int m = 0; m < 32; ++m) {
            float w = W2[k * 32 + m];
            aij[m] = fmaf(zij, w, aij[m]);
            aji[m] = fmaf(zji, w, aji[m]);
        }
    }

    // ---- layer 3: relu then dot with W3 (b3 cancels) ----
    float sij = 0.f, sji = 0.f;
#pragma unroll
    for (int m = 0; m < 32; ++m) {
        float w3 = W3[m];
        sij = fmaf(fmaxf(aij[m], 0.f), w3, sij);
        sji = fmaf(fmaxf(aji[m], 0.f), w3, sji);
    }

    float val = (sij - sji) * mval;

    // ---- reduction over j per row ----
    sVal[r][j] = val;
    __syncthreads();
    if (tid < 256) {
        int rr = tid >> 6;            // wave id == row (64 threads/wave)
        int l  = tid & 63;
        float s = sVal[rr][l] + (l < 32 ? sVal[rr][64 + l] : 0.f);
#pragma unroll
        for (int off = 32; off > 0; off >>= 1) s += __shfl_xor(s, off);
        if (l == 0) qout[bi0 + rr] = qin[bi0 + rr] + s;
    }
}

// ---------------------------------------------------------------------------
extern "C" void kernel_launch(void* const* d_in, const int* in_sizes, int n_in,
                              void* d_out, int out_size, void* d_ws, size_t ws_size,
                              hipStream_t stream) {
    const float* h    = (const float*)d_in[0];
    const float* e    = (const float*)d_in[1];
    const float* q    = (const float*)d_in[2];
    const float* mask = (const float*)d_in[3];
    const float* W1   = (const float*)d_in[4];
    const float* b1   = (const float*)d_in[5];
    const float* W2   = (const float*)d_in[6];
    const float* b2   = (const float*)d_in[7];
    const float* W3   = (const float*)d_in[8];
    // d_in[9] = b3: cancels exactly in (elec_ij - elec_ji); unused.

    float* u = (float*)d_ws;               // BN*32 floats
    float* v = u + BN * 32;                // BN*32 floats
    float* qout = (float*)d_out;           // BN floats

    uv_kernel<<<(BN * 32 + 255) / 256, 256, 0, stream>>>(h, q, W1, b1, u, v);
    edge_kernel<<<BN / 4, 384, 0, stream>>>(e, mask, q, W1, W2, b2, W3, u, v, qout);
}

// Round 8
// 108.312 us; speedup vs baseline: 1.2241x; 1.2241x over previous
//
#include <hip/hip_runtime.h>

#define NATOM 96
#define EDIM  16
#define HDIM  64
#define NMOL  32
#define BN    (NMOL * NATOM)   // 3072 atom-rows

typedef short bf16x8 __attribute__((ext_vector_type(8)));   // 8 bf16 in 4 VGPRs
typedef float f32x16 __attribute__((ext_vector_type(16)));  // 32x32 MFMA C/D

union FragU { unsigned int u[4]; bf16x8 v; };

// pack two f32 into one dword of 2 bf16 (truncation round): [hi | lo]
__device__ inline unsigned int pack_bf16(float lo, float hi) {
    return __builtin_amdgcn_perm(__float_as_uint(hi), __float_as_uint(lo), 0x07060302);
}

// ---------------------------------------------------------------------------
// Kernel 1: per-atom precompute  u_a = x_a@W1[0:65]+b1,  v_a = x_a@W1[65:130]
// ---------------------------------------------------------------------------
__global__ void uv_kernel(const float* __restrict__ h,
                          const float* __restrict__ q,
                          const float* __restrict__ W1,
                          const float* __restrict__ b1,
                          float* __restrict__ u,
                          float* __restrict__ v) {
    int id = blockIdx.x * 256 + threadIdx.x;
    if (id >= BN * 32) return;
    int a = id >> 5;
    int m = id & 31;
    const float* ha = h + (size_t)a * HDIM;
    float qa = q[a];
    float su = b1[m];
    float sv = 0.f;
#pragma unroll 8
    for (int f = 0; f < HDIM; ++f) {
        float hf = ha[f];
        su = fmaf(hf, W1[f * 32 + m], su);
        sv = fmaf(hf, W1[(65 + f) * 32 + m], sv);
    }
    su = fmaf(qa, W1[64 * 32 + m], su);
    sv = fmaf(qa, W1[129 * 32 + m], sv);
    u[id] = su;
    v[id] = sv;
}

// ---------------------------------------------------------------------------
// Kernel 2 (MFMA): block = 384 thr = 6 waves; block owns 2 atom-rows (b,i);
// wave w: row r = w/3, j-block jb = w%3 (32 pairs). Per wave:
//   t^T[unit][pair]  = mfma(A1=W1c^T, B=e^T)                  (1 MFMA)
//   z1 = relu(t + u_i + v_j) / relu(t + u_j + v_i)            (VALU, f32)
//   Z2^T = mfma(A2=W2^T, B=z1^T, C=b2)   2 k-tiles x 2 dirs   (4 MFMA)
//   s = relu(Z2)^T . W3 per pair; antisym, mask, reduce over j.
// C/D map (verified): col=lane&31, row=(reg&3)+8*(reg>>2)+4*(lane>>5).
// ---------------------------------------------------------------------------
__global__ __launch_bounds__(384) void epn_kernel(
    const float* __restrict__ e,
    const float* __restrict__ mask,
    const float* __restrict__ qin,
    const float* __restrict__ W1,
    const float* __restrict__ W2,
    const float* __restrict__ b2,
    const float* __restrict__ W3,
    const float* __restrict__ u,
    const float* __restrict__ v,
    float* __restrict__ qout)
{
    __shared__ float sRed[6];

    const int tid  = threadIdx.x;
    const int w    = tid >> 6;        // wave 0..5
    const int lane = tid & 63;
    const int c    = lane & 31;       // pair-column within group
    const int hh   = lane >> 5;       // lane half

    const int r   = w / 3;            // row within block (0..1)
    const int jb  = w - 3 * r;        // j-block (0..2)
    const int bi  = blockIdx.x * 2 + r;          // global row (b*96+i)
    const int b   = bi / NATOM;
    const int j   = jb * 32 + c;
    const int aj  = b * NATOM + j;               // global atom index of j
    const long p  = (long)bi * NATOM + j;        // pair index

    // ---- mask early (hide latency) ----
    float mval = mask[p];

    // ---- A1 = W1c^T fragment: A[row=c][k=8hh+e] = W1[(130+8hh+e)*32+c] ----
    const float* W1c = W1 + 130 * 32;
    FragU A1;
#pragma unroll
    for (int ee = 0; ee < 4; ++ee) {
        float lo = W1c[(8 * hh + 2 * ee    ) * 32 + c];
        float hi = W1c[(8 * hh + 2 * ee + 1) * 32 + c];
        A1.u[ee] = pack_bf16(lo, hi);
    }

    // ---- A2 k-tiles: A[row=c][k=16kt+8hh+e] = W2[(16kt+8hh+e)*32+c] ----
    FragU A2_0, A2_1;
#pragma unroll
    for (int ee = 0; ee < 4; ++ee) {
        float lo = W2[(8 * hh + 2 * ee    ) * 32 + c];
        float hi = W2[(8 * hh + 2 * ee + 1) * 32 + c];
        A2_0.u[ee] = pack_bf16(lo, hi);
    }
#pragma unroll
    for (int ee = 0; ee < 4; ++ee) {
        float lo = W2[(16 + 8 * hh + 2 * ee    ) * 32 + c];
        float hi = W2[(16 + 8 * hh + 2 * ee + 1) * 32 + c];
        A2_1.u[ee] = pack_bf16(lo, hi);
    }

    // ---- per-reg row constants: rows 4hh+8s+{0..3} for s=reg>>2 ----
    float w3a[16], b2a[16];
#pragma unroll
    for (int s = 0; s < 4; ++s) {
        float4 t4 = *(const float4*)(W3 + 4 * hh + 8 * s);
        w3a[4*s] = t4.x; w3a[4*s+1] = t4.y; w3a[4*s+2] = t4.z; w3a[4*s+3] = t4.w;
        float4 t5 = *(const float4*)(b2 + 4 * hh + 8 * s);
        b2a[4*s] = t5.x; b2a[4*s+1] = t5.y; b2a[4*s+2] = t5.z; b2a[4*s+3] = t5.w;
    }

    // ---- e fragment: B[k=feat 8hh+e][col=pair c] = e[p][8hh+e] ----
    const float* ep = e + p * EDIM + 8 * hh;
    float4 e0 = *(const float4*)(ep);
    float4 e1 = *(const float4*)(ep + 4);
    FragU Be;
    Be.u[0] = pack_bf16(e0.x, e0.y);
    Be.u[1] = pack_bf16(e0.z, e0.w);
    Be.u[2] = pack_bf16(e1.x, e1.y);
    Be.u[3] = pack_bf16(e1.z, e1.w);

    // ---- layer-1 e-part: t^T = W1c^T @ e^T ----
    f32x16 d1;
#pragma unroll
    for (int k = 0; k < 16; ++k) d1[k] = 0.f;
    d1 = __builtin_amdgcn_mfma_f32_32x32x16_bf16(A1.v, Be.v, d1, 0, 0, 0);

    // ---- u/v columns (rows 4hh+8s+{0..3}) ----
    float ui[16], vi[16], uj[16], vj[16];
    {
        const float* ub  = u + (long)bi * 32 + 4 * hh;
        const float* vb  = v + (long)bi * 32 + 4 * hh;
        const float* ujb = u + (long)aj * 32 + 4 * hh;
        const float* vjb = v + (long)aj * 32 + 4 * hh;
#pragma unroll
        for (int s = 0; s < 4; ++s) {
            float4 t4 = *(const float4*)(ub + 8 * s);
            ui[4*s] = t4.x; ui[4*s+1] = t4.y; ui[4*s+2] = t4.z; ui[4*s+3] = t4.w;
            float4 t5 = *(const float4*)(vb + 8 * s);
            vi[4*s] = t5.x; vi[4*s+1] = t5.y; vi[4*s+2] = t5.z; vi[4*s+3] = t5.w;
            float4 t6 = *(const float4*)(ujb + 8 * s);
            uj[4*s] = t6.x; uj[4*s+1] = t6.y; uj[4*s+2] = t6.z; uj[4*s+3] = t6.w;
            float4 t7 = *(const float4*)(vjb + 8 * s);
            vj[4*s] = t7.x; vj[4*s+1] = t7.y; vj[4*s+2] = t7.z; vj[4*s+3] = t7.w;
        }
    }

    // ---- z1 both directions (f32), reg k <-> row (k&3)+8*(k>>2)+4hh ----
    float zij[16], zji[16];
#pragma unroll
    for (int k = 0; k < 16; ++k) {
        float t = d1[k];
        zij[k] = fmaxf(t + ui[k] + vj[k], 0.f);
        zji[k] = fmaxf(t + uj[k] + vi[k], 0.f);
    }

    // ---- repack z1 -> B-frags (unit rows -> k elems), per direction:
    // own rows (k order): 4hh+{0..3}, 8+4hh+{0..3}, 16+4hh+{0..3}, 24+4hh+{0..3}
    // kt0 needs units 8hh+{0..7}; kt1 needs units 16+8hh+{0..7}.
    FragU Bij0, Bij1, Bji0, Bji1;
    {
        unsigned a0 = pack_bf16(zij[0],  zij[1]),  a1 = pack_bf16(zij[2],  zij[3]);
        unsigned b0 = pack_bf16(zij[4],  zij[5]),  b1 = pack_bf16(zij[6],  zij[7]);
        unsigned c0 = pack_bf16(zij[8],  zij[9]),  c1 = pack_bf16(zij[10], zij[11]);
        unsigned d0 = pack_bf16(zij[12], zij[13]), d1p = pack_bf16(zij[14], zij[15]);
        unsigned pa0 = __shfl_xor((int)a0, 32), pa1 = __shfl_xor((int)a1, 32);
        unsigned pb0 = __shfl_xor((int)b0, 32), pb1 = __shfl_xor((int)b1, 32);
        unsigned pc0 = __shfl_xor((int)c0, 32), pc1 = __shfl_xor((int)c1, 32);
        unsigned pd0 = __shfl_xor((int)d0, 32), pd1 = __shfl_xor((int)d1p, 32);
        Bij0.u[0] = hh ? pb0 : a0;   Bij0.u[1] = hh ? pb1 : a1;
        Bij0.u[2] = hh ? b0  : pa0;  Bij0.u[3] = hh ? b1  : pa1;
        Bij1.u[0] = hh ? pd0 : c0;   Bij1.u[1] = hh ? pd1 : c1;
        Bij1.u[2] = hh ? d0  : pc0;  Bij1.u[3] = hh ? d1p : pc1;
    }
    {
        unsigned a0 = pack_bf16(zji[0],  zji[1]),  a1 = pack_bf16(zji[2],  zji[3]);
        unsigned b0 = pack_bf16(zji[4],  zji[5]),  b1 = pack_bf16(zji[6],  zji[7]);
        unsigned c0 = pack_bf16(zji[8],  zji[9]),  c1 = pack_bf16(zji[10], zji[11]);
        unsigned d0 = pack_bf16(zji[12], zji[13]), d1p = pack_bf16(zji[14], zji[15]);
        unsigned pa0 = __shfl_xor((int)a0, 32), pa1 = __shfl_xor((int)a1, 32);
        unsigned pb0 = __shfl_xor((int)b0, 32), pb1 = __shfl_xor((int)b1, 32);
        unsigned pc0 = __shfl_xor((int)c0, 32), pc1 = __shfl_xor((int)c1, 32);
        unsigned pd0 = __shfl_xor((int)d0, 32), pd1 = __shfl_xor((int)d1p, 32);
        Bji0.u[0] = hh ? pb0 : a0;   Bji0.u[1] = hh ? pb1 : a1;
        Bji0.u[2] = hh ? b0  : pa0;  Bji0.u[3] = hh ? b1  : pa1;
        Bji1.u[0] = hh ? pd0 : c0;   Bji1.u[1] = hh ? pd1 : c1;
        Bji1.u[2] = hh ? d0  : pc0;  Bji1.u[3] = hh ? d1p : pc1;
    }

    // ---- layer 2: Z2^T = W2^T @ Z1^T + b2 ----
    f32x16 aij, aji;
#pragma unroll
    for (int k = 0; k < 16; ++k) { aij[k] = b2a[k]; aji[k] = b2a[k]; }
    aij = __builtin_amdgcn_mfma_f32_32x32x16_bf16(A2_0.v, Bij0.v, aij, 0, 0, 0);
    aij = __builtin_amdgcn_mfma_f32_32x32x16_bf16(A2_1.v, Bij1.v, aij, 0, 0, 0);
    aji = __builtin_amdgcn_mfma_f32_32x32x16_bf16(A2_0.v, Bji0.v, aji, 0, 0, 0);
    aji = __builtin_amdgcn_mfma_f32_32x32x16_bf16(A2_1.v, Bji1.v, aji, 0, 0, 0);

    // ---- layer 3: s = relu(z2) . W3 (this lane's 16 rows) ----
    float sij = 0.f, sji = 0.f;
#pragma unroll
    for (int k = 0; k < 16; ++k) {
        sij = fmaf(fmaxf(aij[k], 0.f), w3a[k], sij);
        sji = fmaf(fmaxf(aji[k], 0.f), w3a[k], sji);
    }
    float diff = sij - sji;
    diff += __shfl_xor(diff, 32);     // combine row-halves: full s_ij - s_ji
    float val = diff * mval;

    // ---- sum over the 32 pairs (halves hold identical values) ----
    val += __shfl_xor(val, 16);
    val += __shfl_xor(val, 8);
    val += __shfl_xor(val, 4);
    val += __shfl_xor(val, 2);
    val += __shfl_xor(val, 1);
    if (lane == 0) sRed[w] = val;
    __syncthreads();

    if (tid < 2) {
        int row = tid;
        int bio = blockIdx.x * 2 + row;
        qout[bio] = qin[bio] + sRed[3 * row] + sRed[3 * row + 1] + sRed[3 * row + 2];
    }
}

// ---------------------------------------------------------------------------
extern "C" void kernel_launch(void* const* d_in, const int* in_sizes, int n_in,
                              void* d_out, int out_size, void* d_ws, size_t ws_size,
                              hipStream_t stream) {
    const float* h    = (const float*)d_in[0];
    const float* e    = (const float*)d_in[1];
    const float* q    = (const float*)d_in[2];
    const float* mask = (const float*)d_in[3];
    const float* W1   = (const float*)d_in[4];
    const float* b1   = (const float*)d_in[5];
    const float* W2   = (const float*)d_in[6];
    const float* b2   = (const float*)d_in[7];
    const float* W3   = (const float*)d_in[8];
    // d_in[9] = b3: cancels exactly in (elec_ij - elec_ji); unused.

    float* u = (float*)d_ws;               // BN*32 floats
    float* v = u + BN * 32;                // BN*32 floats
    float* qout = (float*)d_out;           // BN floats

    uv_kernel<<<(BN * 32 + 255) / 256, 256, 0, stream>>>(h, q, W1, b1, u, v);
    epn_kernel<<<BN / 2, 384, 0, stream>>>(e, mask, q, W1, W2, b2, W3, u, v, qout);
}

// Round 10
// 102.978 us; speedup vs baseline: 1.2875x; 1.0518x over previous
//
#include <hip/hip_runtime.h>

#define NATOM 96
#define EDIM  16
#define HDIM  64
#define NMOL  32
#define BN    (NMOL * NATOM)   // 3072 atom-rows

typedef short bf16x8 __attribute__((ext_vector_type(8)));   // 8 bf16 in 4 VGPRs
typedef float f32x16 __attribute__((ext_vector_type(16)));  // 32x32 MFMA C/D

union FragU { unsigned int u[4]; bf16x8 v; };

// pack two f32 into one dword of 2 bf16 (truncation round): [hi | lo]
__device__ inline unsigned int pack_bf16(float lo, float hi) {
    return __builtin_amdgcn_perm(__float_as_uint(hi), __float_as_uint(lo), 0x07060302);
}

// ---------------------------------------------------------------------------
// Kernel 1: per-atom precompute  u_a = x_a@W1[0:65]+b1,  v_a = x_a@W1[65:130]
// ---------------------------------------------------------------------------
__global__ void uv_kernel(const float* __restrict__ h,
                          const float* __restrict__ q,
                          const float* __restrict__ W1,
                          const float* __restrict__ b1,
                          float* __restrict__ u,
                          float* __restrict__ v) {
    int id = blockIdx.x * 256 + threadIdx.x;
    if (id >= BN * 32) return;
    int a = id >> 5;
    int m = id & 31;
    const float* ha = h + (size_t)a * HDIM;
    float qa = q[a];
    float su = b1[m];
    float sv = 0.f;
#pragma unroll 8
    for (int f = 0; f < HDIM; ++f) {
        float hf = ha[f];
        su = fmaf(hf, W1[f * 32 + m], su);
        sv = fmaf(hf, W1[(65 + f) * 32 + m], sv);
    }
    su = fmaf(qa, W1[64 * 32 + m], su);
    sv = fmaf(qa, W1[129 * 32 + m], sv);
    u[id] = su;
    v[id] = sv;
}

// ---------------------------------------------------------------------------
// Kernel 2 (MFMA): block = 384 thr = 6 waves; block owns 2 atom-rows (b,i);
// wave w: row r = w/3, j-block jb = w%3 (32 pairs each). Register-pressure
// restructured: u/v consumed directly into z (no 64-reg staging); b2 folded
// into the epilogue relu (loaded after the MFMAs); launch_bounds(384,4)
// caps VGPR ~128 for ~4.5 waves/SIMD.
// C/D map (verified): col=lane&31, row=(reg&3)+8*(reg>>2)+4*(lane>>5).
// ---------------------------------------------------------------------------
__global__ __launch_bounds__(384, 4) void epn_kernel(
    const float* __restrict__ e,
    const float* __restrict__ mask,
    const float* __restrict__ qin,
    const float* __restrict__ W1,
    const float* __restrict__ W2,
    const float* __restrict__ b2,
    const float* __restrict__ W3,
    const float* __restrict__ u,
    const float* __restrict__ v,
    float* __restrict__ qout)
{
    __shared__ float sRed[6];

    const int tid  = threadIdx.x;
    const int w    = tid >> 6;        // wave 0..5
    const int lane = tid & 63;
    const int c    = lane & 31;       // pair-column within group
    const int hh   = lane >> 5;       // lane half

    const int r   = w / 3;            // row within block (0..1)
    const int jb  = w - 3 * r;        // j-block (0..2)
    const int bi  = blockIdx.x * 2 + r;          // global row (b*96+i)
    const int b   = bi / NATOM;
    const int j   = jb * 32 + c;
    const int aj  = b * NATOM + j;               // global atom index of j
    const long p  = (long)bi * NATOM + j;        // pair index

    // ---- e fragment: B[k=feat 8hh+e][col=pair c] = e[p][8hh+e] ----
    const float* ep = e + p * EDIM + 8 * hh;
    float4 e0 = *(const float4*)(ep);
    float4 e1 = *(const float4*)(ep + 4);
    FragU Be;
    Be.u[0] = pack_bf16(e0.x, e0.y);
    Be.u[1] = pack_bf16(e0.z, e0.w);
    Be.u[2] = pack_bf16(e1.x, e1.y);
    Be.u[3] = pack_bf16(e1.z, e1.w);

    // ---- A1 = W1c^T fragment: A[row=c][k=8hh+e] = W1[(130+8hh+e)*32+c] ----
    const float* W1c = W1 + 130 * 32;
    FragU A1;
#pragma unroll
    for (int ee = 0; ee < 4; ++ee) {
        float lo = W1c[(8 * hh + 2 * ee    ) * 32 + c];
        float hi = W1c[(8 * hh + 2 * ee + 1) * 32 + c];
        A1.u[ee] = pack_bf16(lo, hi);
    }

    // ---- layer-1 e-part: t^T = W1c^T @ e^T ----
    f32x16 d1;
#pragma unroll
    for (int k = 0; k < 16; ++k) d1[k] = 0.f;
    d1 = __builtin_amdgcn_mfma_f32_32x32x16_bf16(A1.v, Be.v, d1, 0, 0, 0);

    // ---- A2 k-tiles: A[row=c][k=16kt+8hh+e] = W2[(16kt+8hh+e)*32+c] ----
    FragU A2_0, A2_1;
#pragma unroll
    for (int ee = 0; ee < 4; ++ee) {
        float lo = W2[(8 * hh + 2 * ee    ) * 32 + c];
        float hi = W2[(8 * hh + 2 * ee + 1) * 32 + c];
        A2_0.u[ee] = pack_bf16(lo, hi);
    }
#pragma unroll
    for (int ee = 0; ee < 4; ++ee) {
        float lo = W2[(16 + 8 * hh + 2 * ee    ) * 32 + c];
        float hi = W2[(16 + 8 * hh + 2 * ee + 1) * 32 + c];
        A2_1.u[ee] = pack_bf16(lo, hi);
    }

    // ---- z1 both directions (f32): consume u/v float4s directly ----
    // reg k <-> unit row (k&3)+8*(k>>2)+4hh; loads at offset 4hh+8s.
    const float* ub  = u + (long)bi * 32 + 4 * hh;
    const float* vb  = v + (long)bi * 32 + 4 * hh;
    const float* ujb = u + (long)aj * 32 + 4 * hh;
    const float* vjb = v + (long)aj * 32 + 4 * hh;
    float zij[16], zji[16];
#pragma unroll
    for (int s = 0; s < 4; ++s) {
        float4 uiv = *(const float4*)(ub  + 8 * s);
        float4 viv = *(const float4*)(vb  + 8 * s);
        float4 ujv = *(const float4*)(ujb + 8 * s);
        float4 vjv = *(const float4*)(vjb + 8 * s);
        zij[4*s+0] = fmaxf(d1[4*s+0] + uiv.x + vjv.x, 0.f);
        zij[4*s+1] = fmaxf(d1[4*s+1] + uiv.y + vjv.y, 0.f);
        zij[4*s+2] = fmaxf(d1[4*s+2] + uiv.z + vjv.z, 0.f);
        zij[4*s+3] = fmaxf(d1[4*s+3] + uiv.w + vjv.w, 0.f);
        zji[4*s+0] = fmaxf(d1[4*s+0] + ujv.x + viv.x, 0.f);
        zji[4*s+1] = fmaxf(d1[4*s+1] + ujv.y + viv.y, 0.f);
        zji[4*s+2] = fmaxf(d1[4*s+2] + ujv.z + viv.z, 0.f);
        zji[4*s+3] = fmaxf(d1[4*s+3] + ujv.w + viv.w, 0.f);
    }

    // ---- repack z1 -> B-frags (unit rows -> k elems), per direction ----
    FragU Bij0, Bij1, Bji0, Bji1;
    {
        unsigned a0 = pack_bf16(zij[0],  zij[1]),  a1 = pack_bf16(zij[2],  zij[3]);
        unsigned b0 = pack_bf16(zij[4],  zij[5]),  b1 = pack_bf16(zij[6],  zij[7]);
        unsigned c0 = pack_bf16(zij[8],  zij[9]),  c1 = pack_bf16(zij[10], zij[11]);
        unsigned d0 = pack_bf16(zij[12], zij[13]), d1p = pack_bf16(zij[14], zij[15]);
        unsigned pa0 = __shfl_xor((int)a0, 32), pa1 = __shfl_xor((int)a1, 32);
        unsigned pb0 = __shfl_xor((int)b0, 32), pb1 = __shfl_xor((int)b1, 32);
        unsigned pc0 = __shfl_xor((int)c0, 32), pc1 = __shfl_xor((int)c1, 32);
        unsigned pd0 = __shfl_xor((int)d0, 32), pd1 = __shfl_xor((int)d1p, 32);
        Bij0.u[0] = hh ? pb0 : a0;   Bij0.u[1] = hh ? pb1 : a1;
        Bij0.u[2] = hh ? b0  : pa0;  Bij0.u[3] = hh ? b1  : pa1;
        Bij1.u[0] = hh ? pd0 : c0;   Bij1.u[1] = hh ? pd1 : c1;
        Bij1.u[2] = hh ? d0  : pc0;  Bij1.u[3] = hh ? d1p : pc1;
    }
    {
        unsigned a0 = pack_bf16(zji[0],  zji[1]),  a1 = pack_bf16(zji[2],  zji[3]);
        unsigned b0 = pack_bf16(zji[4],  zji[5]),  b1 = pack_bf16(zji[6],  zji[7]);
        unsigned c0 = pack_bf16(zji[8],  zji[9]),  c1 = pack_bf16(zji[10], zji[11]);
        unsigned d0 = pack_bf16(zji[12], zji[13]), d1p = pack_bf16(zji[14], zji[15]);
        unsigned pa0 = __shfl_xor((int)a0, 32), pa1 = __shfl_xor((int)a1, 32);
        unsigned pb0 = __shfl_xor((int)b0, 32), pb1 = __shfl_xor((int)b1, 32);
        unsigned pc0 = __shfl_xor((int)c0, 32), pc1 = __shfl_xor((int)c1, 32);
        unsigned pd0 = __shfl_xor((int)d0, 32), pd1 = __shfl_xor((int)d1p, 32);
        Bji0.u[0] = hh ? pb0 : a0;   Bji0.u[1] = hh ? pb1 : a1;
        Bji0.u[2] = hh ? b0  : pa0;  Bji0.u[3] = hh ? b1  : pa1;
        Bji1.u[0] = hh ? pd0 : c0;   Bji1.u[1] = hh ? pd1 : c1;
        Bji1.u[2] = hh ? d0  : pc0;  Bji1.u[3] = hh ? d1p : pc1;
    }

    // ---- layer 2: Z2^T = W2^T @ Z1^T (b2 folded into epilogue) ----
    f32x16 aij, aji;
#pragma unroll
    for (int k = 0; k < 16; ++k) { aij[k] = 0.f; aji[k] = 0.f; }
    aij = __builtin_amdgcn_mfma_f32_32x32x16_bf16(A2_0.v, Bij0.v, aij, 0, 0, 0);
    aij = __builtin_amdgcn_mfma_f32_32x32x16_bf16(A2_1.v, Bij1.v, aij, 0, 0, 0);
    aji = __builtin_amdgcn_mfma_f32_32x32x16_bf16(A2_0.v, Bji0.v, aji, 0, 0, 0);
    aji = __builtin_amdgcn_mfma_f32_32x32x16_bf16(A2_1.v, Bji1.v, aji, 0, 0, 0);

    // ---- layer 3: s = relu(z2 + b2) . W3, loaded late (float4 chunks) ----
    float sij = 0.f, sji = 0.f;
#pragma unroll
    for (int s = 0; s < 4; ++s) {
        float4 bb = *(const float4*)(b2 + 4 * hh + 8 * s);
        float4 ww = *(const float4*)(W3 + 4 * hh + 8 * s);
        sij = fmaf(fmaxf(aij[4*s+0] + bb.x, 0.f), ww.x, sij);
        sij = fmaf(fmaxf(aij[4*s+1] + bb.y, 0.f), ww.y, sij);
        sij = fmaf(fmaxf(aij[4*s+2] + bb.z, 0.f), ww.z, sij);
        sij = fmaf(fmaxf(aij[4*s+3] + bb.w, 0.f), ww.w, sij);
        sji = fmaf(fmaxf(aji[4*s+0] + bb.x, 0.f), ww.x, sji);
        sji = fmaf(fmaxf(aji[4*s+1] + bb.y, 0.f), ww.y, sji);
        sji = fmaf(fmaxf(aji[4*s+2] + bb.z, 0.f), ww.z, sji);
        sji = fmaf(fmaxf(aji[4*s+3] + bb.w, 0.f), ww.w, sji);
    }
    float diff = sij - sji;
    diff += __shfl_xor(diff, 32);     // combine row-halves: full s_ij - s_ji
    float val = diff * mask[p];

    // ---- sum over the 32 pairs (halves hold identical values) ----
    val += __shfl_xor(val, 16);
    val += __shfl_xor(val, 8);
    val += __shfl_xor(val, 4);
    val += __shfl_xor(val, 2);
    val += __shfl_xor(val, 1);
    if (lane == 0) sRed[w] = val;
    __syncthreads();

    if (tid < 2) {
        int row = tid;
        int bio = blockIdx.x * 2 + row;
        qout[bio] = qin[bio] + sRed[3 * row] + sRed[3 * row + 1] + sRed[3 * row + 2];
    }
}

// ---------------------------------------------------------------------------
extern "C" void kernel_launch(void* const* d_in, const int* in_sizes, int n_in,
                              void* d_out, int out_size, void* d_ws, size_t ws_size,
                              hipStream_t stream) {
    const float* h    = (const float*)d_in[0];
    const float* e    = (const float*)d_in[1];
    const float* q    = (const float*)d_in[2];
    const float* mask = (const float*)d_in[3];
    const float* W1   = (const float*)d_in[4];
    const float* b1   = (const float*)d_in[5];
    const float* W2   = (const float*)d_in[6];
    const float* b2   = (const float*)d_in[7];
    const float* W3   = (const float*)d_in[8];
    // d_in[9] = b3: cancels exactly in (elec_ij - elec_ji); unused.

    float* u = (float*)d_ws;               // BN*32 floats
    float* v = u + BN * 32;                // BN*32 floats
    float* qout = (float*)d_out;           // BN floats

    uv_kernel<<<(BN * 32 + 255) / 256, 256, 0, stream>>>(h, q, W1, b1, u, v);
    epn_kernel<<<BN / 2, 384, 0, stream>>>(e, mask, q, W1, W2, b2, W3, u, v, qout);
}

// Round 14
// 96.108 us; speedup vs baseline: 1.3795x; 1.0715x over previous
//
#include <hip/hip_runtime.h>

#define NATOM 96
#define EDIM  16
#define HDIM  64
#define NMOL  32
#define BN    (NMOL * NATOM)   // 3072 atom-rows

typedef short bf16x8 __attribute__((ext_vector_type(8)));   // 8 bf16 in 4 VGPRs
typedef float f32x16 __attribute__((ext_vector_type(16)));  // 32x32 MFMA C/D

union FragU { unsigned int u[4]; bf16x8 v; };

// pack two f32 into one dword of 2 bf16 (truncation round): [hi | lo]
__device__ inline unsigned int pack_bf16(float lo, float hi) {
    return __builtin_amdgcn_perm(__float_as_uint(hi), __float_as_uint(lo), 0x07060302);
}

// ---------------------------------------------------------------------------
// Kernel 1: per-atom precompute  u_a = x_a@W1[0:65]+b1,  v_a = x_a@W1[65:130]
// ---------------------------------------------------------------------------
__global__ void uv_kernel(const float* __restrict__ h,
                          const float* __restrict__ q,
                          const float* __restrict__ W1,
                          const float* __restrict__ b1,
                          float* __restrict__ u,
                          float* __restrict__ v) {
    int id = blockIdx.x * 256 + threadIdx.x;
    if (id >= BN * 32) return;
    int a = id >> 5;
    int m = id & 31;
    const float* ha = h + (size_t)a * HDIM;
    float qa = q[a];
    float su = b1[m];
    float sv = 0.f;
#pragma unroll 8
    for (int f = 0; f < HDIM; ++f) {
        float hf = ha[f];
        su = fmaf(hf, W1[f * 32 + m], su);
        sv = fmaf(hf, W1[(65 + f) * 32 + m], sv);
    }
    su = fmaf(qa, W1[64 * 32 + m], su);
    sv = fmaf(qa, W1[129 * 32 + m], sv);
    u[id] = su;
    v[id] = sv;
}

// ---------------------------------------------------------------------------
// Kernel 2 (MFMA + LDS-staged u/v): block = 384 thr = 6 waves = 2 i-rows x
// 3 j-blocks; both i-rows share one molecule, so u/v for the molecule's 96
// atoms are staged coalesced into LDS ([96][36] pad -> b128 gather at LDS
// BW floor) killing the 128B-stride global gathers (32 lines/inst -> 0).
// e/mask remain direct global loads. b2 folded into epilogue.
// C/D map (verified): col=lane&31, row=(reg&3)+8*(reg>>2)+4*(lane>>5).
// ---------------------------------------------------------------------------
__global__ __launch_bounds__(384, 4) void epn_kernel(
    const float* __restrict__ e,
    const float* __restrict__ mask,
    const float* __restrict__ qin,
    const float* __restrict__ W1,
    const float* __restrict__ W2,
    const float* __restrict__ b2,
    const float* __restrict__ W3,
    const float* __restrict__ u,
    const float* __restrict__ v,
    float* __restrict__ qout)
{
    __shared__ float sU[NATOM][36];
    __shared__ float sV[NATOM][36];
    __shared__ float sRed[6];

    const int tid  = threadIdx.x;
    const int w    = tid >> 6;        // wave 0..5
    const int lane = tid & 63;
    const int c    = lane & 31;       // pair-column within group
    const int hh   = lane >> 5;       // lane half

    const int r   = w / 3;            // row within block (0..1)
    const int jb  = w - 3 * r;        // j-block (0..2)
    const int bi  = blockIdx.x * 2 + r;          // global row (b*96+i)
    const int b   = bi / NATOM;
    const int il  = bi - b * NATOM;              // local atom index of i
    const int j   = jb * 32 + c;
    const long p  = (long)bi * NATOM + j;        // pair index

    // ---- e fragment: B[k=feat 8hh+e][col=pair c] = e[p][8hh+e] ----
    const float* ep = e + p * EDIM + 8 * hh;
    float4 e0 = *(const float4*)(ep);
    float4 e1 = *(const float4*)(ep + 4);
    FragU Be;
    Be.u[0] = pack_bf16(e0.x, e0.y);
    Be.u[1] = pack_bf16(e0.z, e0.w);
    Be.u[2] = pack_bf16(e1.x, e1.y);
    Be.u[3] = pack_bf16(e1.z, e1.w);

    // ---- A1 = W1c^T fragment: A[row=c][k=8hh+e] = W1[(130+8hh+e)*32+c] ----
    const float* W1c = W1 + 130 * 32;
    FragU A1;
#pragma unroll
    for (int ee = 0; ee < 4; ++ee) {
        float lo = W1c[(8 * hh + 2 * ee    ) * 32 + c];
        float hi = W1c[(8 * hh + 2 * ee + 1) * 32 + c];
        A1.u[ee] = pack_bf16(lo, hi);
    }

    // ---- A2 k-tiles: A[row=c][k=16kt+8hh+e] = W2[(16kt+8hh+e)*32+c] ----
    FragU A2_0, A2_1;
#pragma unroll
    for (int ee = 0; ee < 4; ++ee) {
        float lo = W2[(8 * hh + 2 * ee    ) * 32 + c];
        float hi = W2[(8 * hh + 2 * ee + 1) * 32 + c];
        A2_0.u[ee] = pack_bf16(lo, hi);
    }
#pragma unroll
    for (int ee = 0; ee < 4; ++ee) {
        float lo = W2[(16 + 8 * hh + 2 * ee    ) * 32 + c];
        float hi = W2[(16 + 8 * hh + 2 * ee + 1) * 32 + c];
        A2_1.u[ee] = pack_bf16(lo, hi);
    }

    // ---- stage u/v for the whole molecule into LDS (coalesced reads) ----
    {
        const float* ug = u + (long)b * NATOM * 32;
        const float* vg = v + (long)b * NATOM * 32;
#pragma unroll
        for (int it = 0; it < 2; ++it) {
            int idx  = tid + it * 384;          // 0..767 float4 slots
            int row  = idx >> 3;                // 8 float4 per 32-float row
            int col4 = (idx & 7) << 2;
            *(float4*)&sU[row][col4] = *(const float4*)(ug + row * 32 + col4);
            *(float4*)&sV[row][col4] = *(const float4*)(vg + row * 32 + col4);
        }
    }
    __syncthreads();

    // ---- layer-1 e-part: t^T = W1c^T @ e^T ----
    f32x16 d1;
#pragma unroll
    for (int k = 0; k < 16; ++k) d1[k] = 0.f;
    d1 = __builtin_amdgcn_mfma_f32_32x32x16_bf16(A1.v, Be.v, d1, 0, 0, 0);

    // ---- z1 both directions (f32): u/v from LDS ----
    // reg k <-> unit row (k&3)+8*(k>>2)+4hh; offsets 4hh+8s.
    float zij[16], zji[16];
#pragma unroll
    for (int s = 0; s < 4; ++s) {
        int off = 4 * hh + 8 * s;
        float4 uiv = *(const float4*)&sU[il][off];
        float4 viv = *(const float4*)&sV[il][off];
        float4 ujv = *(const float4*)&sU[j][off];
        float4 vjv = *(const float4*)&sV[j][off];
        zij[4*s+0] = fmaxf(d1[4*s+0] + uiv.x + vjv.x, 0.f);
        zij[4*s+1] = fmaxf(d1[4*s+1] + uiv.y + vjv.y, 0.f);
        zij[4*s+2] = fmaxf(d1[4*s+2] + uiv.z + vjv.z, 0.f);
        zij[4*s+3] = fmaxf(d1[4*s+3] + uiv.w + vjv.w, 0.f);
        zji[4*s+0] = fmaxf(d1[4*s+0] + ujv.x + viv.x, 0.f);
        zji[4*s+1] = fmaxf(d1[4*s+1] + ujv.y + viv.y, 0.f);
        zji[4*s+2] = fmaxf(d1[4*s+2] + ujv.z + viv.z, 0.f);
        zji[4*s+3] = fmaxf(d1[4*s+3] + ujv.w + viv.w, 0.f);
    }

    // ---- repack z1 -> B-frags (unit rows -> k elems), per direction ----
    FragU Bij0, Bij1, Bji0, Bji1;
    {
        unsigned a0 = pack_bf16(zij[0],  zij[1]),  a1 = pack_bf16(zij[2],  zij[3]);
        unsigned b0 = pack_bf16(zij[4],  zij[5]),  b1 = pack_bf16(zij[6],  zij[7]);
        unsigned c0 = pack_bf16(zij[8],  zij[9]),  c1 = pack_bf16(zij[10], zij[11]);
        unsigned d0 = pack_bf16(zij[12], zij[13]), d1p = pack_bf16(zij[14], zij[15]);
        unsigned pa0 = __shfl_xor((int)a0, 32), pa1 = __shfl_xor((int)a1, 32);
        unsigned pb0 = __shfl_xor((int)b0, 32), pb1 = __shfl_xor((int)b1, 32);
        unsigned pc0 = __shfl_xor((int)c0, 32), pc1 = __shfl_xor((int)c1, 32);
        unsigned pd0 = __shfl_xor((int)d0, 32), pd1 = __shfl_xor((int)d1p, 32);
        Bij0.u[0] = hh ? pb0 : a0;   Bij0.u[1] = hh ? pb1 : a1;
        Bij0.u[2] = hh ? b0  : pa0;  Bij0.u[3] = hh ? b1  : pa1;
        Bij1.u[0] = hh ? pd0 : c0;   Bij1.u[1] = hh ? pd1 : c1;
        Bij1.u[2] = hh ? d0  : pc0;  Bij1.u[3] = hh ? d1p : pc1;
    }
    {
        unsigned a0 = pack_bf16(zji[0],  zji[1]),  a1 = pack_bf16(zji[2],  zji[3]);
        unsigned b0 = pack_bf16(zji[4],  zji[5]),  b1 = pack_bf16(zji[6],  zji[7]);
        unsigned c0 = pack_bf16(zji[8],  zji[9]),  c1 = pack_bf16(zji[10], zji[11]);
        unsigned d0 = pack_bf16(zji[12], zji[13]), d1p = pack_bf16(zji[14], zji[15]);
        unsigned pa0 = __shfl_xor((int)a0, 32), pa1 = __shfl_xor((int)a1, 32);
        unsigned pb0 = __shfl_xor((int)b0, 32), pb1 = __shfl_xor((int)b1, 32);
        unsigned pc0 = __shfl_xor((int)c0, 32), pc1 = __shfl_xor((int)c1, 32);
        unsigned pd0 = __shfl_xor((int)d0, 32), pd1 = __shfl_xor((int)d1p, 32);
        Bji0.u[0] = hh ? pb0 : a0;   Bji0.u[1] = hh ? pb1 : a1;
        Bji0.u[2] = hh ? b0  : pa0;  Bji0.u[3] = hh ? b1  : pa1;
        Bji1.u[0] = hh ? pd0 : c0;   Bji1.u[1] = hh ? pd1 : c1;
        Bji1.u[2] = hh ? d0  : pc0;  Bji1.u[3] = hh ? d1p : pc1;
    }

    // ---- layer 2: Z2^T = W2^T @ Z1^T (b2 folded into epilogue) ----
    f32x16 aij, aji;
#pragma unroll
    for (int k = 0; k < 16; ++k) { aij[k] = 0.f; aji[k] = 0.f; }
    aij = __builtin_amdgcn_mfma_f32_32x32x16_bf16(A2_0.v, Bij0.v, aij, 0, 0, 0);
    aij = __builtin_amdgcn_mfma_f32_32x32x16_bf16(A2_1.v, Bij1.v, aij, 0, 0, 0);
    aji = __builtin_amdgcn_mfma_f32_32x32x16_bf16(A2_0.v, Bji0.v, aji, 0, 0, 0);
    aji = __builtin_amdgcn_mfma_f32_32x32x16_bf16(A2_1.v, Bji1.v, aji, 0, 0, 0);

    // ---- layer 3: s = relu(z2 + b2) . W3, loaded late (float4 chunks) ----
    float sij = 0.f, sji = 0.f;
#pragma unroll
    for (int s = 0; s < 4; ++s) {
        float4 bb = *(const float4*)(b2 + 4 * hh + 8 * s);
        float4 ww = *(const float4*)(W3 + 4 * hh + 8 * s);
        sij = fmaf(fmaxf(aij[4*s+0] + bb.x, 0.f), ww.x, sij);
        sij = fmaf(fmaxf(aij[4*s+1] + bb.y, 0.f), ww.y, sij);
        sij = fmaf(fmaxf(aij[4*s+2] + bb.z, 0.f), ww.z, sij);
        sij = fmaf(fmaxf(aij[4*s+3] + bb.w, 0.f), ww.w, sij);
        sji = fmaf(fmaxf(aji[4*s+0] + bb.x, 0.f), ww.x, sji);
        sji = fmaf(fmaxf(aji[4*s+1] + bb.y, 0.f), ww.y, sji);
        sji = fmaf(fmaxf(aji[4*s+2] + bb.z, 0.f), ww.z, sji);
        sji = fmaf(fmaxf(aji[4*s+3] + bb.w, 0.f), ww.w, sji);
    }
    float diff = sij - sji;
    diff += __shfl_xor(diff, 32);     // combine row-halves: full s_ij - s_ji
    float val = diff * mask[p];

    // ---- sum over the 32 pairs (halves hold identical values) ----
    val += __shfl_xor(val, 16);
    val += __shfl_xor(val, 8);
    val += __shfl_xor(val, 4);
    val += __shfl_xor(val, 2);
    val += __shfl_xor(val, 1);
    if (lane == 0) sRed[w] = val;
    __syncthreads();

    if (tid < 2) {
        int row = tid;
        int bio = blockIdx.x * 2 + row;
        qout[bio] = qin[bio] + sRed[3 * row] + sRed[3 * row + 1] + sRed[3 * row + 2];
    }
}

// ---------------------------------------------------------------------------
extern "C" void kernel_launch(void* const* d_in, const int* in_sizes, int n_in,
                              void* d_out, int out_size, void* d_ws, size_t ws_size,
                              hipStream_t stream) {
    const float* h    = (const float*)d_in[0];
    const float* e    = (const float*)d_in[1];
    const float* q    = (const float*)d_in[2];
    const float* mask = (const float*)d_in[3];
    const float* W1   = (const float*)d_in[4];
    const float* b1   = (const float*)d_in[5];
    const float* W2   = (const float*)d_in[6];
    const float* b2   = (const float*)d_in[7];
    const float* W3   = (const float*)d_in[8];
    // d_in[9] = b3: cancels exactly in (elec_ij - elec_ji); unused.

    float* u = (float*)d_ws;               // BN*32 floats
    float* v = u + BN * 32;                // BN*32 floats
    float* qout = (float*)d_out;           // BN floats

    uv_kernel<<<(BN * 32 + 255) / 256, 256, 0, stream>>>(h, q, W1, b1, u, v);
    epn_kernel<<<BN / 2, 384, 0, stream>>>(e, mask, q, W1, W2, b2, W3, u, v, qout);
}